// Round 5
// baseline (278.710 us; speedup 1.0000x reference)
//
#include <hip/hip_runtime.h>
#include <math.h>

// Problem constants
#define NB 32768
#define NC 100
#define NK 8
#define ND 512
#define ALPHA 22.0f      // Neumann split: Ahat = ALPHA*(I - M); eig(Ahat) in [19.8, ~24.3]
#define NEU_ITERS 12

typedef __attribute__((ext_vector_type(8))) short short8;
typedef __attribute__((ext_vector_type(4))) float f32x4;

__device__ __forceinline__ void gl_lds16(const void* g, void* l) {
    __builtin_amdgcn_global_load_lds(
        (const __attribute__((address_space(1))) void*)g,
        (__attribute__((address_space(3))) void*)l, 16, 0, 0);
}

__device__ __forceinline__ float warpReduceSum(float v) {
#pragma unroll
    for (int off = 32; off > 0; off >>= 1) v += __shfl_xor(v, off);
    return v;
}

__device__ float blockReduceSum256(float v, float* red) {
    int tid = threadIdx.x;
    v = warpReduceSum(v);
    __syncthreads();
    if ((tid & 63) == 0) red[tid >> 6] = v;
    __syncthreads();
    return red[0] + red[1] + red[2] + red[3];
}

__device__ __forceinline__ unsigned short f2bf(float x) {
    unsigned u = __float_as_uint(x);
    u = (u + 0x7FFFu + ((u >> 16) & 1u)) >> 16;
    return (unsigned short)u;
}
__device__ __forceinline__ float bf2f(unsigned short h) {
    return __uint_as_float(((unsigned)h) << 16);
}

// ------------------------- prep kernels (fp32) -------------------------

// Writes Pn rows, centers (row-major), centersT [512][100], bvec(b_same)
__global__ void k_prep_class(const float* __restrict__ protos, float* __restrict__ X,
                             float* __restrict__ centersT) {
    __shared__ float red[4];
    int c = blockIdx.x;
    int tid = threadIdx.x;
    const float eps = 1e-8f;
    float pv0[NK], pv1[NK];
#pragma unroll
    for (int k = 0; k < NK; ++k) {
        pv0[k] = protos[(c * NK + k) * ND + tid];
        pv1[k] = protos[(c * NK + k) * ND + tid + 256];
    }
    float sv0 = 0.f, sv1 = 0.f;
#pragma unroll
    for (int k = 0; k < NK; ++k) {
        float ss = blockReduceSum256(pv0[k] * pv0[k] + pv1[k] * pv1[k], red);
        float inv = 1.0f / fmaxf(sqrtf(ss), eps);
        pv0[k] *= inv; pv1[k] *= inv;
        X[(c * NK + k) * ND + tid] = pv0[k];
        X[(c * NK + k) * ND + tid + 256] = pv1[k];
        sv0 += pv0[k]; sv1 += pv1[k];
    }
    float ssum = blockReduceSum256(sv0 * sv0 + sv1 * sv1, red);
    float mnorm = sqrtf(ssum) * 0.125f;
    float cinv = 0.125f / fmaxf(mnorm, eps);
    float* centers = X + 800 * ND;
    float c0 = sv0 * cinv, c1 = sv1 * cinv;
    centers[c * ND + tid] = c0;
    centers[c * ND + tid + 256] = c1;
    centersT[tid * NC + c] = c0;
    centersT[(tid + 256) * NC + c] = c1;
    const float ws = 0.5f / 8.0f;
    float* bvec = X + 900 * ND;
    bvec[c * ND + tid] = ws * sv0;
    bvec[c * ND + tid + 256] = ws * sv1;
}

__global__ void k_csum(const float* __restrict__ X, float* __restrict__ csum) {
    int d = blockIdx.x * blockDim.x + threadIdx.x;
    const float* centers = X + 800 * ND;
    float s = 0.f;
    for (int c = 0; c < NC; ++c) s += centers[c * ND + d];
    csum[d] = s;
}

__global__ void k_bopp(float* __restrict__ X, const float* __restrict__ csum) {
    int c = blockIdx.x, tid = threadIdx.x;
    const float wo = 0.5f / 99.0f;
    const float* centers = X + 800 * ND;
    float* bvec = X + 900 * ND;
    for (int d = tid; d < ND; d += 256)
        bvec[c * ND + d] -= wo * (csum[d] - centers[c * ND + d]);
}

// M = I - Ahat/ALPHA, Ahat = (ridge/wo) I + C C^T  (100x100); coalesced via centersT
__global__ void k_gram(const float* __restrict__ X, const float* __restrict__ centersT,
                       float* __restrict__ M) {
    __shared__ float cs[ND];
    int i = blockIdx.x, tid = threadIdx.x;
    const float* centers = X + 800 * ND;
    for (int d = tid; d < ND; d += 128) cs[d] = centers[i * ND + d];
    __syncthreads();
    if (tid < NC) {
        float s = 0.f;
#pragma unroll 8
        for (int d = 0; d < ND; ++d) s += cs[d] * centersT[d * NC + tid];
        float ahat = s + ((tid == i) ? (0.1f * 99.0f / 0.5f) : 0.f);  // +19.8 on diag
        M[i * NC + tid] = ((tid == i) ? 1.f : 0.f) - ahat * (1.0f / ALPHA);
    }
}

// T1[j][i] = centers_i . X_j  (coalesced via centersT)
__global__ void k_T1(const float* __restrict__ X, const float* __restrict__ centersT,
                     float* __restrict__ T1) {
    __shared__ float xs[ND];
    int j = blockIdx.x, tid = threadIdx.x;
    reinterpret_cast<float4*>(xs)[tid] = reinterpret_cast<const float4*>(X + j * ND)[tid];
    __syncthreads();
    if (tid < NC) {
        float s = 0.f;
#pragma unroll 8
        for (int d = 0; d < ND; ++d) s += xs[d] * centersT[d * NC + tid];
        T1[j * NC + tid] = s;
    }
}

// T2[j][:] = Ahat^{-1} T1[j][:] via Neumann
__global__ __launch_bounds__(256) void k_T2neu(const float* __restrict__ M,
                                               const float* __restrict__ T1,
                                               float* __restrict__ T2) {
    __shared__ float Msh[NC * 108];
    __shared__ float pbuf[2][4][104];
    int tid = threadIdx.x;
    int wave = tid >> 6, lane = tid & 63;
    int j = blockIdx.x * 4 + wave;
    for (int idx = tid; idx < NC * NC; idx += 256) {
        int i = idx / NC, m = idx - i * NC;
        Msh[i * 108 + m] = M[idx];
    }
    int i0 = lane;
    int i1 = lane + 64;
    int i1c = (i1 < NC) ? i1 : 0;
    float t0 = T1[j * NC + i0];
    float t1v = (i1 < NC) ? T1[j * NC + i1] : 0.f;
    float s0 = t0, s1 = t1v;
    pbuf[0][wave][i0] = t0;
    if (i1 < NC) pbuf[0][wave][i1] = t1v;
    __syncthreads();
    int cur = 0;
    for (int it = 0; it < NEU_ITERS; ++it) {
        const float* p = pbuf[cur][wave];
        float y0 = 0.f, y1 = 0.f;
#pragma unroll 5
        for (int m = 0; m < NC; m += 4) {
            float4 pv = *reinterpret_cast<const float4*>(p + m);
            float4 a0 = *reinterpret_cast<const float4*>(&Msh[i0 * 108 + m]);
            float4 a1 = *reinterpret_cast<const float4*>(&Msh[i1c * 108 + m]);
            y0 = fmaf(a0.x, pv.x, y0); y0 = fmaf(a0.y, pv.y, y0);
            y0 = fmaf(a0.z, pv.z, y0); y0 = fmaf(a0.w, pv.w, y0);
            y1 = fmaf(a1.x, pv.x, y1); y1 = fmaf(a1.y, pv.y, y1);
            y1 = fmaf(a1.z, pv.z, y1); y1 = fmaf(a1.w, pv.w, y1);
        }
        s0 += y0; s1 += y1;
        int nxt = cur ^ 1;
        pbuf[nxt][wave][i0] = y0;
        if (i1 < NC) pbuf[nxt][wave][i1] = y1;
        cur = nxt;
    }
    T2[j * NC + i0] = s0 * (1.0f / ALPHA);
    if (i1 < NC) T2[j * NC + i1] = s1 * (1.0f / ALPHA);
}

__global__ void k_Y(const float* __restrict__ X, const float* __restrict__ T2,
                    float* __restrict__ Y) {
    __shared__ float t2s[NC];
    int j = blockIdx.x, tid = threadIdx.x;
    for (int i = tid; i < NC; i += 256) t2s[i] = T2[j * NC + i];
    __syncthreads();
    const float* centers = X + 800 * ND;
    for (int d = tid; d < ND; d += 256) {
        float s = 0.f;
        for (int i = 0; i < NC; ++i) s += centers[i * ND + d] * t2s[i];
        Y[j * ND + d] = (X[j * ND + d] - s) * 10.0f;
    }
}

__global__ void k_solve(const float* __restrict__ X, const float* __restrict__ Y,
                        float* __restrict__ W) {
    __shared__ float Vs[9 * 516];
    __shared__ float Ys[10 * 516];
    __shared__ float SL[9 * 10];
    __shared__ float zL[9];
    int c = blockIdx.x, tid = threadIdx.x;
    for (int idx = tid; idx < 9 * 128; idx += 256) {
        int a = idx >> 7, q = idx & 127;
        int row = (a < 8) ? (c * 8 + a) : (800 + c);
        reinterpret_cast<float4*>(&Vs[a * 516])[q] =
            reinterpret_cast<const float4*>(X + row * ND)[q];
    }
    for (int idx = tid; idx < 10 * 128; idx += 256) {
        int a = idx >> 7, q = idx & 127;
        int row = (a < 8) ? (c * 8 + a) : ((a == 8) ? (800 + c) : (900 + c));
        reinterpret_cast<float4*>(&Ys[a * 516])[q] =
            reinterpret_cast<const float4*>(Y + row * ND)[q];
    }
    __syncthreads();
    if (tid < 90) {
        int a = tid / 10, bb = tid - (tid / 10) * 10;
        float s = 0.f;
        for (int d = 0; d < ND; ++d) s += Vs[a * 516 + d] * Ys[bb * 516 + d];
        if (bb == a) s += 16.0f;
        if (bb == a && a == 8) s += -198.0f - 16.0f;
        SL[tid] = s;
    }
    __syncthreads();
    if (tid == 0) {
        for (int p = 0; p < 9; ++p) {
            int best = p; float bv = fabsf(SL[p * 10 + p]);
            for (int r = p + 1; r < 9; ++r) {
                float v = fabsf(SL[r * 10 + p]);
                if (v > bv) { bv = v; best = r; }
            }
            if (best != p)
                for (int j = p; j < 10; ++j) {
                    float t = SL[p * 10 + j]; SL[p * 10 + j] = SL[best * 10 + j]; SL[best * 10 + j] = t;
                }
            float ip = 1.0f / SL[p * 10 + p];
            for (int r = p + 1; r < 9; ++r) {
                float f = SL[r * 10 + p] * ip;
                for (int j = p; j < 10; ++j) SL[r * 10 + j] -= f * SL[p * 10 + j];
            }
        }
        for (int p = 8; p >= 0; --p) {
            float s = SL[p * 10 + 9];
            for (int j = p + 1; j < 9; ++j) s -= SL[p * 10 + j] * zL[j];
            zL[p] = s / SL[p * 10 + p];
        }
    }
    __syncthreads();
    for (int d = tid; d < ND; d += 256) {
        float w = Ys[9 * 516 + d];
#pragma unroll
        for (int a = 0; a < 9; ++a) w -= zL[a] * Ys[a * 516 + d];
        W[c * ND + d] = w;
    }
}

// ------------------------- bf16 packing -------------------------

__global__ void k_hn(const float* __restrict__ h, unsigned short* __restrict__ hnb) {
    int tid = threadIdx.x;
    int wave = tid >> 6, lane = tid & 63;
    int r = blockIdx.x * 4 + wave;
    const float4* hp = reinterpret_cast<const float4*>(h + (size_t)r * ND);
    float4 v0 = hp[lane * 2];
    float4 v1 = hp[lane * 2 + 1];
    float s = v0.x * v0.x + v0.y * v0.y + v0.z * v0.z + v0.w * v0.w
            + v1.x * v1.x + v1.y * v1.y + v1.z * v1.z + v1.w * v1.w;
    s = warpReduceSum(s);
    float inv = 1.0f / fmaxf(sqrtf(s), 1e-8f);
    uint4 o;
    o.x = (unsigned)f2bf(v0.x * inv) | ((unsigned)f2bf(v0.y * inv) << 16);
    o.y = (unsigned)f2bf(v0.z * inv) | ((unsigned)f2bf(v0.w * inv) << 16);
    o.z = (unsigned)f2bf(v1.x * inv) | ((unsigned)f2bf(v1.y * inv) << 16);
    o.w = (unsigned)f2bf(v1.z * inv) | ((unsigned)f2bf(v1.w * inv) << 16);
    reinterpret_cast<uint4*>(hnb + (size_t)r * ND)[lane] = o;
}

__global__ void k_packB(const float* __restrict__ X, const float* __restrict__ W,
                        unsigned short* __restrict__ Bp) {
    int tid = threadIdx.x;
    int row = blockIdx.x * 4 + (tid >> 6);
    int lane = tid & 63;
    int c = row / 10, j = row - c * 10;
    float vals[8];
    if (c >= NC) {
#pragma unroll
        for (int q = 0; q < 8; ++q) vals[q] = 0.f;
    } else if (j < 8) {
        const float* src = X + (size_t)(c * 8 + j) * ND + lane * 8;
#pragma unroll
        for (int q = 0; q < 8; ++q) vals[q] = src[q];
    } else {
        const float* src = W + (size_t)c * ND + lane * 8;
#pragma unroll
        for (int q = 0; q < 8; ++q) {
            float w = src[q];
            vals[q] = (j == 8) ? w : (w - bf2f(f2bf(w)));
        }
    }
    uint4 o;
    o.x = (unsigned)f2bf(vals[0]) | ((unsigned)f2bf(vals[1]) << 16);
    o.y = (unsigned)f2bf(vals[2]) | ((unsigned)f2bf(vals[3]) << 16);
    o.z = (unsigned)f2bf(vals[4]) | ((unsigned)f2bf(vals[5]) << 16);
    o.w = (unsigned)f2bf(vals[6]) | ((unsigned)f2bf(vals[7]) << 16);
    reinterpret_cast<uint4*>(Bp + (size_t)row * ND)[lane] = o;
}

// ------------------------- main MFMA GEMM + fused epilogue -------------------------
// 128 rows x 160 cols per block, BK=64, 4 waves x (4 row-tiles x 5 col-tiles) 16x16x32.
// A/B staged via global_load_lds width=16; unpadded rows (64 shorts) with XOR octet
// swizzle: element (row, octet o) at LDS slot (o ^ (row&7)) -> conflict-free b128 reads.
// LDS: union{ As[128*64] + Bs[160*64] bf16 (36 KB) | Cs[64*163] f32 (41.7 KB) }.

__global__ __launch_bounds__(256, 3) void k_main_mfma(
        const unsigned short* __restrict__ hnb, const unsigned short* __restrict__ Bp,
        float* __restrict__ out) {
    __shared__ __align__(16) char smem[41728];
    unsigned short* As = (unsigned short*)smem;          // 128*64 shorts = 16 KB
    unsigned short* Bs = (unsigned short*)smem + 8192;   // 160*64 shorts = 20 KB
    float* Cs = (float*)smem;                            // 64*163 floats = 41728 B

    int tid = threadIdx.x;
    int wave = tid >> 6, lane = tid & 63;
    int m = lane & 15, g = lane >> 4;
    int rs = m & 7;
    int rowhalf = wave & 1, colhalf = wave >> 1;
    int cb = blockIdx.x;
    int r0 = blockIdx.y * 128;

    int rsub = lane >> 3;            // row within 8-row chunk
    int osw = (lane & 7) ^ rsub;     // swizzled source k-octet

    f32x4 acc[4][5] = {};

    for (int kc = 0; kc < 8; ++kc) {
        __syncthreads();
        // async stage A: 16 chunks (8 rows x 128 B each), 4 per wave
#pragma unroll
        for (int q = 0; q < 4; ++q) {
            int ch = wave * 4 + q;
            const unsigned short* gp =
                hnb + (size_t)(r0 + ch * 8 + rsub) * ND + kc * 64 + osw * 8;
            gl_lds16(gp, As + ch * 512);
        }
        // async stage B: 20 chunks, 5 per wave
#pragma unroll
        for (int q = 0; q < 5; ++q) {
            int ch = wave * 5 + q;
            const unsigned short* gp =
                Bp + (size_t)(cb * 160 + ch * 8 + rsub) * ND + kc * 64 + osw * 8;
            gl_lds16(gp, Bs + ch * 512);
        }
        __syncthreads();
#pragma unroll
        for (int kk = 0; kk < 2; ++kk) {
            short8 af[4], bfr[5];
#pragma unroll
            for (int rt = 0; rt < 4; ++rt)
                af[rt] = *reinterpret_cast<const short8*>(
                    As + (rowhalf * 64 + rt * 16 + m) * 64 + (((kk << 2) + g) ^ rs) * 8);
#pragma unroll
            for (int ct = 0; ct < 5; ++ct)
                bfr[ct] = *reinterpret_cast<const short8*>(
                    Bs + (colhalf * 80 + ct * 16 + m) * 64 + (((kk << 2) + g) ^ rs) * 8);
#pragma unroll
            for (int rt = 0; rt < 4; ++rt)
#pragma unroll
                for (int ct = 0; ct < 5; ++ct)
                    acc[rt][ct] = __builtin_amdgcn_mfma_f32_16x16x32_bf16(
                        af[rt], bfr[ct], acc[rt][ct], 0, 0, 0);
        }
    }

    // fused epilogue: two 64-row passes through LDS (C/D: col=lane&15, row=g*4+reg)
    for (int p = 0; p < 2; ++p) {
        __syncthreads();
        if (rowhalf == p) {
#pragma unroll
            for (int rt = 0; rt < 4; ++rt)
#pragma unroll
                for (int ct = 0; ct < 5; ++ct)
#pragma unroll
                    for (int reg = 0; reg < 4; ++reg) {
                        int lr = rt * 16 + g * 4 + reg;
                        int lc = colhalf * 80 + ct * 16 + m;
                        Cs[lr * 163 + lc] = acc[rt][ct][reg];
                    }
        }
        __syncthreads();
        {
            int cl = tid & 15;
            int c = cb * 16 + cl;
#pragma unroll
            for (int q = 0; q < 4; ++q) {
                int r = (tid >> 4) + q * 16;
                float v[10];
#pragma unroll
                for (int j = 0; j < 10; ++j) v[j] = Cs[r * 163 + cl * 10 + j];
                float mx = v[0];
#pragma unroll
                for (int j = 1; j < 8; ++j) mx = fmaxf(mx, v[j]);
                float se = 0.f, sec = 0.f;
#pragma unroll
                for (int j = 0; j < 8; ++j) {
                    float e = __expf((v[j] - mx) * 20.0f);  // 1/SUB_T
                    se += e; sec += e * v[j];
                }
                float res = v[8] + v[9];
                if (c < NC)
                    out[(size_t)(r0 + p * 64 + r) * NC + c] =
                        (sec / se + res) * (1.0f / 0.07f);
            }
        }
    }
}

extern "C" void kernel_launch(void* const* d_in, const int* in_sizes, int n_in,
                              void* d_out, int out_size, void* d_ws, size_t ws_size,
                              hipStream_t stream) {
    (void)in_sizes; (void)n_in; (void)out_size; (void)ws_size;
    const float* h = (const float*)d_in[0];
    const float* protos = (const float*)d_in[1];
    float* out = (float*)d_out;
    float* ws = (float*)d_ws;

    float* X        = ws;                  // 512000  (Pn | centers | bvec)
    float* csum     = X + 512000;          // 512
    float* M        = csum + 512;          // 10000
    float* T1       = M + 10000;           // 100000  [1000][100]
    float* T2       = T1 + 100000;         // 100000  [1000][100]
    float* Y        = T2 + 100000;         // 512000
    float* W        = Y + 512000;          // 51200
    float* centersT = W + 51200;           // 51200   [512][100]
    unsigned short* hnb = (unsigned short*)(centersT + 51200);  // 32768*512 bf16
    unsigned short* Bp  = hnb + (size_t)NB * ND;                // 1120*512 bf16

    k_hn<<<NB / 4, 256, 0, stream>>>(h, hnb);
    k_prep_class<<<NC, 256, 0, stream>>>(protos, X, centersT);
    k_csum<<<2, 256, 0, stream>>>(X, csum);
    k_bopp<<<NC, 256, 0, stream>>>(X, csum);
    k_gram<<<NC, 128, 0, stream>>>(X, centersT, M);
    k_T1<<<1000, 128, 0, stream>>>(X, centersT, T1);
    k_T2neu<<<250, 256, 0, stream>>>(M, T1, T2);
    k_Y<<<1000, 256, 0, stream>>>(X, T2, Y);
    k_solve<<<NC, 256, 0, stream>>>(X, Y, W);
    k_packB<<<280, 256, 0, stream>>>(X, W, Bp);
    dim3 grid(7, NB / 128);
    k_main_mfma<<<grid, 256, 0, stream>>>(hnb, Bp, out);
}

// Round 6
// 241.346 us; speedup vs baseline: 1.1548x; 1.1548x over previous
//
#include <hip/hip_runtime.h>
#include <math.h>

// Problem constants
#define NB 32768
#define NC 100
#define NK 8
#define ND 512
#define ALPHA 22.0f      // Neumann split: Ahat = ALPHA*(I - M); eig(Ahat) in [19.8, ~24.3]
#define NEU_ITERS 12
// Pipeline (7 launches):
//  k_hn         hnb = bf16(h/||h||)                     [32768,512]
//  k_prep_class Pn/centers/centersT/b_same + Bp proto rows (bf16)
//  k_csbopp     bvec = b_same - wo*(csum - center)       (csum recomputed per block)
//  k_T1M        T1[j][i] = centers_i . X_j  (j=0..999)  + M from center rows
//  k_T2neu      T2 = Ahat^{-1} T1 via Neumann
//  k_solveW     per class: G(raw grams), S=(G-T1.T2)/r, 9x9 solve, W=(u-C^T q)/r
//               -> writes Bp W_hi/W_lo rows (+ zero pad slots)
//  k_main_mfma  64x160-tile bf16 MFMA GEMM, dbuf async staging, fused softmax

typedef __attribute__((ext_vector_type(8))) short short8;
typedef __attribute__((ext_vector_type(4))) float f32x4;

__device__ __forceinline__ void gl_lds16(const void* g, void* l) {
    __builtin_amdgcn_global_load_lds(
        (const __attribute__((address_space(1))) void*)g,
        (__attribute__((address_space(3))) void*)l, 16, 0, 0);
}

__device__ __forceinline__ float warpReduceSum(float v) {
#pragma unroll
    for (int off = 32; off > 0; off >>= 1) v += __shfl_xor(v, off);
    return v;
}

__device__ float blockReduceSum256(float v, float* red) {
    int tid = threadIdx.x;
    v = warpReduceSum(v);
    __syncthreads();
    if ((tid & 63) == 0) red[tid >> 6] = v;
    __syncthreads();
    return red[0] + red[1] + red[2] + red[3];
}

__device__ __forceinline__ unsigned short f2bf(float x) {
    unsigned u = __float_as_uint(x);
    u = (u + 0x7FFFu + ((u >> 16) & 1u)) >> 16;
    return (unsigned short)u;
}
__device__ __forceinline__ float bf2f(unsigned short h) {
    return __uint_as_float(((unsigned)h) << 16);
}

// ------------------------- prep kernels (fp32) -------------------------

// Pn rows + centers + centersT + b_same; also packs Bp proto rows (bf16)
__global__ void k_prep_class(const float* __restrict__ protos, float* __restrict__ X,
                             float* __restrict__ centersT, unsigned short* __restrict__ Bp) {
    __shared__ float red[4];
    int c = blockIdx.x;
    int tid = threadIdx.x;
    const float eps = 1e-8f;
    float pv0[NK], pv1[NK];
#pragma unroll
    for (int k = 0; k < NK; ++k) {
        pv0[k] = protos[(c * NK + k) * ND + tid];
        pv1[k] = protos[(c * NK + k) * ND + tid + 256];
    }
    float sv0 = 0.f, sv1 = 0.f;
#pragma unroll
    for (int k = 0; k < NK; ++k) {
        float ss = blockReduceSum256(pv0[k] * pv0[k] + pv1[k] * pv1[k], red);
        float inv = 1.0f / fmaxf(sqrtf(ss), eps);
        pv0[k] *= inv; pv1[k] *= inv;
        X[(c * NK + k) * ND + tid] = pv0[k];
        X[(c * NK + k) * ND + tid + 256] = pv1[k];
        Bp[(size_t)(c * 10 + k) * ND + tid] = f2bf(pv0[k]);
        Bp[(size_t)(c * 10 + k) * ND + tid + 256] = f2bf(pv1[k]);
        sv0 += pv0[k]; sv1 += pv1[k];
    }
    float ssum = blockReduceSum256(sv0 * sv0 + sv1 * sv1, red);
    float mnorm = sqrtf(ssum) * 0.125f;
    float cinv = 0.125f / fmaxf(mnorm, eps);
    float* centers = X + 800 * ND;
    float c0 = sv0 * cinv, c1 = sv1 * cinv;
    centers[c * ND + tid] = c0;
    centers[c * ND + tid + 256] = c1;
    centersT[tid * NC + c] = c0;
    centersT[(tid + 256) * NC + c] = c1;
    const float ws = 0.5f / 8.0f;
    float* bvec = X + 900 * ND;
    bvec[c * ND + tid] = ws * sv0;
    bvec[c * ND + tid + 256] = ws * sv1;
}

// bvec_c -= wo*(csum - center_c); csum computed in-block (cheap, L2-hot)
__global__ void k_csbopp(float* __restrict__ X) {
    int c = blockIdx.x, tid = threadIdx.x;
    const float wo = 0.5f / 99.0f;
    const float* centers = X + 800 * ND;
    float* bvec = X + 900 * ND;
#pragma unroll
    for (int h = 0; h < 2; ++h) {
        int d = tid + h * 256;
        float s = 0.f;
#pragma unroll 4
        for (int i = 0; i < NC; ++i) s += centers[i * ND + d];
        bvec[c * ND + d] -= wo * (s - centers[c * ND + d]);
    }
}

// T1[j][i] = centers_i . X_j for j=0..999; rows 800..899 also emit M = I - Ahat/ALPHA
__global__ __launch_bounds__(256) void k_T1M(const float* __restrict__ X,
                                             const float* __restrict__ centersT,
                                             float* __restrict__ T1, float* __restrict__ M) {
    __shared__ float xs[4][ND];
    int tid = threadIdx.x;
    int wave = tid >> 6, lane = tid & 63;
    int j = blockIdx.x * 4 + wave;
    reinterpret_cast<float4*>(xs[wave])[lane * 2] =
        reinterpret_cast<const float4*>(X + (size_t)j * ND)[lane * 2];
    reinterpret_cast<float4*>(xs[wave])[lane * 2 + 1] =
        reinterpret_cast<const float4*>(X + (size_t)j * ND)[lane * 2 + 1];
    __syncthreads();
    int i0 = lane, i1 = lane + 64;
    int i1c = (i1 < NC) ? i1 : 0;
    float s0 = 0.f, s1 = 0.f;
#pragma unroll 8
    for (int d = 0; d < ND; ++d) {
        float xv = xs[wave][d];
        s0 = fmaf(xv, centersT[d * NC + i0], s0);
        s1 = fmaf(xv, centersT[d * NC + i1c], s1);
    }
    T1[j * NC + i0] = s0;
    if (i1 < NC) T1[j * NC + i1] = s1;
    if (j >= 800 && j < 900) {
        int ci = j - 800;
        float a0 = s0 + ((i0 == ci) ? 19.8f : 0.f);
        M[ci * NC + i0] = ((i0 == ci) ? 1.f : 0.f) - a0 * (1.0f / ALPHA);
        if (i1 < NC) {
            float a1 = s1 + ((i1 == ci) ? 19.8f : 0.f);
            M[ci * NC + i1] = ((i1 == ci) ? 1.f : 0.f) - a1 * (1.0f / ALPHA);
        }
    }
}

// T2[j][:] = Ahat^{-1} T1[j][:] via Neumann
__global__ __launch_bounds__(256) void k_T2neu(const float* __restrict__ M,
                                               const float* __restrict__ T1,
                                               float* __restrict__ T2) {
    __shared__ float Msh[NC * 108];
    __shared__ float pbuf[2][4][104];
    int tid = threadIdx.x;
    int wave = tid >> 6, lane = tid & 63;
    int j = blockIdx.x * 4 + wave;
    for (int idx = tid; idx < NC * NC; idx += 256) {
        int i = idx / NC, m = idx - i * NC;
        Msh[i * 108 + m] = M[idx];
    }
    int i0 = lane;
    int i1 = lane + 64;
    int i1c = (i1 < NC) ? i1 : 0;
    float t0 = T1[j * NC + i0];
    float t1v = (i1 < NC) ? T1[j * NC + i1] : 0.f;
    float s0 = t0, s1 = t1v;
    pbuf[0][wave][i0] = t0;
    if (i1 < NC) pbuf[0][wave][i1] = t1v;
    __syncthreads();
    int cur = 0;
    for (int it = 0; it < NEU_ITERS; ++it) {
        const float* p = pbuf[cur][wave];
        float y0 = 0.f, y1 = 0.f;
#pragma unroll 5
        for (int m = 0; m < NC; m += 4) {
            float4 pv = *reinterpret_cast<const float4*>(p + m);
            float4 a0 = *reinterpret_cast<const float4*>(&Msh[i0 * 108 + m]);
            float4 a1 = *reinterpret_cast<const float4*>(&Msh[i1c * 108 + m]);
            y0 = fmaf(a0.x, pv.x, y0); y0 = fmaf(a0.y, pv.y, y0);
            y0 = fmaf(a0.z, pv.z, y0); y0 = fmaf(a0.w, pv.w, y0);
            y1 = fmaf(a1.x, pv.x, y1); y1 = fmaf(a1.y, pv.y, y1);
            y1 = fmaf(a1.z, pv.z, y1); y1 = fmaf(a1.w, pv.w, y1);
        }
        s0 += y0; s1 += y1;
        int nxt = cur ^ 1;
        pbuf[nxt][wave][i0] = y0;
        if (i1 < NC) pbuf[nxt][wave][i1] = y1;
        cur = nxt;
    }
    T2[j * NC + i0] = s0 * (1.0f / ALPHA);
    if (i1 < NC) T2[j * NC + i1] = s1 * (1.0f / ALPHA);
}

// Per class: G = raw 10x10 gram; S = (G - T1.T2)/ridge + D^{-1}; solve 9x9 -> z;
// W = (u - C^T q)/ridge, u = bvec - sum z_a V_a, q = T2[bvec] - sum z_a T2[a].
// Writes Bp rows c*10+8 (W_hi) and c*10+9 (W_lo). c>=100: zero-fill pad slots.
__global__ __launch_bounds__(256) void k_solveW(const float* __restrict__ X,
                                                const float* __restrict__ T1,
                                                const float* __restrict__ T2,
                                                unsigned short* __restrict__ Bp) {
    int c = blockIdx.x, tid = threadIdx.x;
    if (c >= NC) {  // zero pad slots 100..111
        uint4 z = {0, 0, 0, 0};
        for (int idx = tid; idx < 10 * ND / 8; idx += 256)
            reinterpret_cast<uint4*>(Bp + (size_t)c * 10 * ND)[idx] = z;
        return;
    }
    __shared__ float Xs[10 * 516];
    __shared__ float T1s[10 * 104];
    __shared__ float T2s[10 * 104];
    __shared__ float G[10][10];
    __shared__ float SL[9 * 10];
    __shared__ float zL[9];
    __shared__ float q[104];
    // row index map: a<8 -> proto, a==8 -> center, a==9 -> bvec
    for (int idx = tid; idx < 10 * 128; idx += 256) {
        int a = idx >> 7, p = idx & 127;
        int row = (a < 8) ? (c * 8 + a) : ((a == 8) ? (800 + c) : (900 + c));
        reinterpret_cast<float4*>(&Xs[a * 516])[p] =
            reinterpret_cast<const float4*>(X + (size_t)row * ND)[p];
    }
    for (int idx = tid; idx < 10 * NC; idx += 256) {
        int a = idx / NC, i = idx - a * NC;
        int row = (a < 8) ? (c * 8 + a) : ((a == 8) ? (800 + c) : (900 + c));
        T1s[a * 104 + i] = T1[row * NC + i];
        T2s[a * 104 + i] = T2[row * NC + i];
    }
    __syncthreads();
    if (tid < 100) {
        int a = tid / 10, b = tid - (tid / 10) * 10;
        float s = 0.f;
        for (int d = 0; d < ND; ++d) s += Xs[a * 516 + d] * Xs[b * 516 + d];
        G[a][b] = s;
    }
    __syncthreads();
    if (tid < 90) {
        int a = tid / 10, b = tid - (tid / 10) * 10;
        float s = 0.f;
#pragma unroll 4
        for (int i = 0; i < NC; ++i) s += T1s[a * 104 + i] * T2s[b * 104 + i];
        float val = (G[a][b] - s) * 10.0f;   // 1/ridge
        if (b == a) val += (a < 8) ? 16.0f : -198.0f;  // D^{-1}
        SL[tid] = val;
    }
    __syncthreads();
    if (tid == 0) {
        for (int p = 0; p < 9; ++p) {
            int best = p; float bv = fabsf(SL[p * 10 + p]);
            for (int r = p + 1; r < 9; ++r) {
                float v = fabsf(SL[r * 10 + p]);
                if (v > bv) { bv = v; best = r; }
            }
            if (best != p)
                for (int j = p; j < 10; ++j) {
                    float t = SL[p * 10 + j]; SL[p * 10 + j] = SL[best * 10 + j]; SL[best * 10 + j] = t;
                }
            float ip = 1.0f / SL[p * 10 + p];
            for (int r = p + 1; r < 9; ++r) {
                float f = SL[r * 10 + p] * ip;
                for (int j = p; j < 10; ++j) SL[r * 10 + j] -= f * SL[p * 10 + j];
            }
        }
        for (int p = 8; p >= 0; --p) {
            float s = SL[p * 10 + 9];
            for (int j = p + 1; j < 9; ++j) s -= SL[p * 10 + j] * zL[j];
            zL[p] = s / SL[p * 10 + p];
        }
    }
    __syncthreads();
    if (tid < NC) {
        float s = T2s[9 * 104 + tid];
#pragma unroll
        for (int a = 0; a < 9; ++a) s -= zL[a] * T2s[a * 104 + tid];
        q[tid] = s;
    }
    __syncthreads();
    const float* centers = X + 800 * ND;
#pragma unroll
    for (int h = 0; h < 2; ++h) {
        int d = tid + h * 256;
        float u = Xs[9 * 516 + d];
#pragma unroll
        for (int a = 0; a < 9; ++a) u -= zL[a] * Xs[a * 516 + d];
        float s = 0.f;
#pragma unroll 4
        for (int i = 0; i < NC; ++i) s = fmaf(centers[i * ND + d], q[i], s);
        float w = (u - s) * 10.0f;
        unsigned short hi = f2bf(w);
        Bp[(size_t)(c * 10 + 8) * ND + d] = hi;
        Bp[(size_t)(c * 10 + 9) * ND + d] = f2bf(w - bf2f(hi));
    }
}

// ------------------------- bf16 input normalization -------------------------

__global__ void k_hn(const float* __restrict__ h, unsigned short* __restrict__ hnb) {
    int tid = threadIdx.x;
    int wave = tid >> 6, lane = tid & 63;
    int r = blockIdx.x * 4 + wave;
    const float4* hp = reinterpret_cast<const float4*>(h + (size_t)r * ND);
    float4 v0 = hp[lane * 2];
    float4 v1 = hp[lane * 2 + 1];
    float s = v0.x * v0.x + v0.y * v0.y + v0.z * v0.z + v0.w * v0.w
            + v1.x * v1.x + v1.y * v1.y + v1.z * v1.z + v1.w * v1.w;
    s = warpReduceSum(s);
    float inv = 1.0f / fmaxf(sqrtf(s), 1e-8f);
    uint4 o;
    o.x = (unsigned)f2bf(v0.x * inv) | ((unsigned)f2bf(v0.y * inv) << 16);
    o.y = (unsigned)f2bf(v0.z * inv) | ((unsigned)f2bf(v0.w * inv) << 16);
    o.z = (unsigned)f2bf(v1.x * inv) | ((unsigned)f2bf(v1.y * inv) << 16);
    o.w = (unsigned)f2bf(v1.z * inv) | ((unsigned)f2bf(v1.w * inv) << 16);
    reinterpret_cast<uint4*>(hnb + (size_t)r * ND)[lane] = o;
}

// ------------------------- main MFMA GEMM + fused epilogue -------------------------
// 64 rows x 160 cols per block, BK=64, double-buffered async DMA staging (one
// __syncthreads per kc), XOR-octet swizzled LDS, XCD-aware block swizzle.
// 4 waves: wave (rh,ch) = 32 rows (2 tiles) x 80 cols (5 tiles) of 16x16x32.
// LDS: 2 x (A 8KB + B 20KB) = 56KB; epilogue Cs[64][163] f32 = 41.7KB reuses it.

__global__ __launch_bounds__(256, 2) void k_main_mfma(
        const unsigned short* __restrict__ hnb, const unsigned short* __restrict__ Bp,
        float* __restrict__ out) {
    __shared__ __align__(16) char smem[57344];
    float* Cs = (float*)smem;

    int tid = threadIdx.x;
    int wave = tid >> 6, lane = tid & 63;
    int m = lane & 15, g = lane >> 4;
    int rs = m & 7;
    int rh = wave & 1, ch = wave >> 1;

    // XCD swizzle: the 7 col-blocks of one row-block land on one XCD
    int id = blockIdx.x;
    int xcd = id & 7, kk2 = id >> 3;
    int cb = kk2 % 7;
    int rb = (kk2 / 7) * 8 + xcd;
    int r0 = rb * 64;

    int rsub = lane >> 3;            // row within 8-row chunk
    int osw = (lane & 7) ^ rsub;     // swizzled source k-octet

    f32x4 acc[2][5] = {};

    // stage kc into buffer p (A: 8 chunks/2 per wave; B: 20 chunks/5 per wave)
    auto issue = [&](int kc, int p) {
        unsigned short* As = (unsigned short*)(smem + p * 28672);
        unsigned short* Bs = As + 4096;
#pragma unroll
        for (int q2 = 0; q2 < 2; ++q2) {
            int chk = wave * 2 + q2;
            gl_lds16(hnb + (size_t)(r0 + chk * 8 + rsub) * ND + kc * 64 + osw * 8,
                     As + chk * 512);
        }
#pragma unroll
        for (int q2 = 0; q2 < 5; ++q2) {
            int chk = wave * 5 + q2;
            gl_lds16(Bp + (size_t)(cb * 160 + chk * 8 + rsub) * ND + kc * 64 + osw * 8,
                     Bs + chk * 512);
        }
    };

    issue(0, 0);
    for (int kc = 0; kc < 8; ++kc) {
        int cur = kc & 1;
        __syncthreads();                 // drains own DMAs (vmcnt 0) + barrier
        if (kc < 7) issue(kc + 1, cur ^ 1);
        unsigned short* As = (unsigned short*)(smem + cur * 28672);
        unsigned short* Bs = As + 4096;
#pragma unroll
        for (int kk = 0; kk < 2; ++kk) {
            short8 af[2], bfr[5];
#pragma unroll
            for (int rt = 0; rt < 2; ++rt)
                af[rt] = *reinterpret_cast<const short8*>(
                    As + (rh * 32 + rt * 16 + m) * 64 + (((kk << 2) + g) ^ rs) * 8);
#pragma unroll
            for (int ct = 0; ct < 5; ++ct)
                bfr[ct] = *reinterpret_cast<const short8*>(
                    Bs + (ch * 80 + ct * 16 + m) * 64 + (((kk << 2) + g) ^ rs) * 8);
#pragma unroll
            for (int rt = 0; rt < 2; ++rt)
#pragma unroll
                for (int ct = 0; ct < 5; ++ct)
                    acc[rt][ct] = __builtin_amdgcn_mfma_f32_16x16x32_bf16(
                        af[rt], bfr[ct], acc[rt][ct], 0, 0, 0);
        }
    }

    // single-pass epilogue (C/D layout: col=lane&15, row=g*4+reg)
    __syncthreads();
#pragma unroll
    for (int rt = 0; rt < 2; ++rt)
#pragma unroll
        for (int ct = 0; ct < 5; ++ct)
#pragma unroll
            for (int reg = 0; reg < 4; ++reg) {
                int lr = rh * 32 + rt * 16 + g * 4 + reg;
                int lc = ch * 80 + ct * 16 + m;
                Cs[lr * 163 + lc] = acc[rt][ct][reg];
            }
    __syncthreads();
    {
        int cl = tid & 15;
        int c = cb * 16 + cl;
#pragma unroll
        for (int q2 = 0; q2 < 4; ++q2) {
            int r = (tid >> 4) + q2 * 16;
            float v[10];
#pragma unroll
            for (int j = 0; j < 10; ++j) v[j] = Cs[r * 163 + cl * 10 + j];
            float mx = v[0];
#pragma unroll
            for (int j = 1; j < 8; ++j) mx = fmaxf(mx, v[j]);
            float se = 0.f, sec = 0.f;
#pragma unroll
            for (int j = 0; j < 8; ++j) {
                float e = __expf((v[j] - mx) * 20.0f);  // 1/SUB_T
                se += e; sec += e * v[j];
            }
            float res = v[8] + v[9];
            if (c < NC)
                out[(size_t)(r0 + r) * NC + c] = (sec / se + res) * (1.0f / 0.07f);
        }
    }
}

extern "C" void kernel_launch(void* const* d_in, const int* in_sizes, int n_in,
                              void* d_out, int out_size, void* d_ws, size_t ws_size,
                              hipStream_t stream) {
    (void)in_sizes; (void)n_in; (void)out_size; (void)ws_size;
    const float* h = (const float*)d_in[0];
    const float* protos = (const float*)d_in[1];
    float* out = (float*)d_out;
    float* ws = (float*)d_ws;

    float* X        = ws;                  // 512000 (Pn | centers | bvec)
    float* centersT = X + 512000;          // 51200  [512][100]
    float* M        = centersT + 51200;    // 10000
    float* T1       = M + 10000;           // 100000 [1000][100]
    float* T2       = T1 + 100000;         // 100000 [1000][100]
    unsigned short* hnb = (unsigned short*)(T2 + 100000);   // 32768*512 bf16
    unsigned short* Bp  = hnb + (size_t)NB * ND;            // 1120*512 bf16

    k_hn<<<NB / 4, 256, 0, stream>>>(h, hnb);
    k_prep_class<<<NC, 256, 0, stream>>>(protos, X, centersT, Bp);
    k_csbopp<<<NC, 256, 0, stream>>>(X);
    k_T1M<<<250, 256, 0, stream>>>(X, centersT, T1, M);
    k_T2neu<<<250, 256, 0, stream>>>(M, T1, T2);
    k_solveW<<<112, 256, 0, stream>>>(X, T1, T2, Bp);
    k_main_mfma<<<3584, 256, 0, stream>>>(hnb, Bp, out);
}